// Round 1
// baseline (677.940 us; speedup 1.0000x reference)
//
#include <hip/hip_runtime.h>
#include <math.h>

#define BATCH 2048
#define FID 65536
#define NTHREADS 256

// Kernel 1: one block per batch row. Coalesced float4 dot(gate[b,:], bias),
// block reduction, thread 0 writes logit and pred.
__global__ __launch_bounds__(NTHREADS) void lr_rows(
        const float* __restrict__ gate,
        const float* __restrict__ bias,
        const float* __restrict__ gbias,
        float* __restrict__ out) {
    const int b = blockIdx.x;
    const float4* __restrict__ g4 = (const float4*)(gate + (size_t)b * FID);
    const float4* __restrict__ b4 = (const float4*)bias;

    float acc = 0.0f;
    // FID/4 = 16384 float4s; 256 threads -> 64 iterations each, stride-256 coalesced
    #pragma unroll 4
    for (int i = threadIdx.x; i < FID / 4; i += NTHREADS) {
        float4 g = g4[i];
        float4 v = b4[i];
        acc = fmaf(g.x, v.x, acc);
        acc = fmaf(g.y, v.y, acc);
        acc = fmaf(g.z, v.z, acc);
        acc = fmaf(g.w, v.w, acc);
    }

    // wave64 butterfly reduce
    #pragma unroll
    for (int off = 32; off > 0; off >>= 1)
        acc += __shfl_down(acc, off, 64);

    __shared__ float wsum[NTHREADS / 64];
    const int wave = threadIdx.x >> 6;
    const int lane = threadIdx.x & 63;
    if (lane == 0) wsum[wave] = acc;
    __syncthreads();

    if (threadIdx.x == 0) {
        float s = wsum[0] + wsum[1] + wsum[2] + wsum[3];
        float logit = s + gbias[0];
        out[b] = logit;                                   // logits
        out[BATCH + b] = 1.0f / (1.0f + expf(-logit));    // pred = sigmoid
    }
}

// Kernel 2: recompute per-example xent from stored logits, sum -> loss scalar.
// Deterministic (no atomics), no workspace needed.
__global__ __launch_bounds__(NTHREADS) void lr_loss(
        const float* __restrict__ out_logits,  // d_out base (logits at [0..BATCH))
        const float* __restrict__ label,
        float* __restrict__ loss_out) {        // &d_out[2*BATCH]
    float acc = 0.0f;
    for (int i = threadIdx.x; i < BATCH; i += NTHREADS) {
        float x = out_logits[i];
        float l = label[i];
        acc += fmaxf(x, 0.0f) - x * l + log1pf(expf(-fabsf(x)));
    }
    #pragma unroll
    for (int off = 32; off > 0; off >>= 1)
        acc += __shfl_down(acc, off, 64);

    __shared__ float wsum[NTHREADS / 64];
    const int wave = threadIdx.x >> 6;
    const int lane = threadIdx.x & 63;
    if (lane == 0) wsum[wave] = acc;
    __syncthreads();
    if (threadIdx.x == 0)
        loss_out[0] = wsum[0] + wsum[1] + wsum[2] + wsum[3];
}

extern "C" void kernel_launch(void* const* d_in, const int* in_sizes, int n_in,
                              void* d_out, int out_size, void* d_ws, size_t ws_size,
                              hipStream_t stream) {
    const float* gate   = (const float*)d_in[0];  // [BATCH, FID]
    const float* bias   = (const float*)d_in[1];  // [FID]
    const float* gbias  = (const float*)d_in[2];  // [1]
    const float* label  = (const float*)d_in[3];  // [BATCH]
    float* out = (float*)d_out;                   // [BATCH logits | BATCH pred | 1 loss]

    lr_rows<<<BATCH, NTHREADS, 0, stream>>>(gate, bias, gbias, out);
    lr_loss<<<1, NTHREADS, 0, stream>>>(out, label, out + 2 * BATCH);
}

// Round 3
// 666.164 us; speedup vs baseline: 1.0177x; 1.0177x over previous
//
#include <hip/hip_runtime.h>
#include <math.h>

#define BATCH 2048
#define FID 65536
#define NT 256
#define ROWS 4               // rows per block: bias float4 reused 4x
#define NV (FID / 4)         // 16384 float4 per row

typedef float vf4 __attribute__((ext_vector_type(4)));  // clang vector: OK for nontemporal builtin

// One block handles ROWS consecutive rows. Bias float4 loaded once per
// iteration, reused for all ROWS gate rows (cuts VMEM request rate from
// 2x to 1.25x per useful HBM byte). Gate loads non-temporal: pure stream,
// don't evict L2-resident bias.
__global__ __launch_bounds__(NT) void lr_rows(
        const float* __restrict__ gate,
        const float* __restrict__ bias,
        const float* __restrict__ gbias,
        float* __restrict__ out) {
    const int r0 = blockIdx.x * ROWS;
    const vf4* __restrict__ b4 = (const vf4*)bias;
    const vf4* __restrict__ g4 = (const vf4*)gate + (size_t)r0 * NV;

    float a0 = 0.f, a1 = 0.f, a2 = 0.f, a3 = 0.f;

    #pragma unroll 2
    for (int i = threadIdx.x; i < NV; i += NT) {
        vf4 v  = b4[i];
        vf4 g0 = __builtin_nontemporal_load(&g4[i]);
        vf4 g1 = __builtin_nontemporal_load(&g4[i + NV]);
        vf4 g2 = __builtin_nontemporal_load(&g4[i + 2 * NV]);
        vf4 g3 = __builtin_nontemporal_load(&g4[i + 3 * NV]);
        a0 = fmaf(g0.x, v.x, a0); a0 = fmaf(g0.y, v.y, a0);
        a0 = fmaf(g0.z, v.z, a0); a0 = fmaf(g0.w, v.w, a0);
        a1 = fmaf(g1.x, v.x, a1); a1 = fmaf(g1.y, v.y, a1);
        a1 = fmaf(g1.z, v.z, a1); a1 = fmaf(g1.w, v.w, a1);
        a2 = fmaf(g2.x, v.x, a2); a2 = fmaf(g2.y, v.y, a2);
        a2 = fmaf(g2.z, v.z, a2); a2 = fmaf(g2.w, v.w, a2);
        a3 = fmaf(g3.x, v.x, a3); a3 = fmaf(g3.y, v.y, a3);
        a3 = fmaf(g3.w, v.w, a3); a3 = fmaf(g3.z, v.z, a3);
    }

    // wave64 butterfly reduce, 4 rows in parallel
    #pragma unroll
    for (int off = 32; off > 0; off >>= 1) {
        a0 += __shfl_down(a0, off, 64);
        a1 += __shfl_down(a1, off, 64);
        a2 += __shfl_down(a2, off, 64);
        a3 += __shfl_down(a3, off, 64);
    }

    __shared__ float wsum[NT / 64][ROWS];
    const int wave = threadIdx.x >> 6;
    const int lane = threadIdx.x & 63;
    if (lane == 0) {
        wsum[wave][0] = a0; wsum[wave][1] = a1;
        wsum[wave][2] = a2; wsum[wave][3] = a3;
    }
    __syncthreads();

    if (threadIdx.x < ROWS) {
        const int r = threadIdx.x;
        float s = wsum[0][r] + wsum[1][r] + wsum[2][r] + wsum[3][r];
        float logit = s + gbias[0];
        out[r0 + r] = logit;                                  // logits
        out[BATCH + r0 + r] = 1.0f / (1.0f + expf(-logit));   // pred
    }
}

// Recompute per-example xent from stored logits, sum -> scalar loss.
__global__ __launch_bounds__(NT) void lr_loss(
        const float* __restrict__ out_logits,
        const float* __restrict__ label,
        float* __restrict__ loss_out) {
    float acc = 0.0f;
    for (int i = threadIdx.x; i < BATCH; i += NT) {
        float x = out_logits[i];
        float l = label[i];
        acc += fmaxf(x, 0.0f) - x * l + log1pf(expf(-fabsf(x)));
    }
    #pragma unroll
    for (int off = 32; off > 0; off >>= 1)
        acc += __shfl_down(acc, off, 64);

    __shared__ float wsum[NT / 64];
    const int wave = threadIdx.x >> 6;
    const int lane = threadIdx.x & 63;
    if (lane == 0) wsum[wave] = acc;
    __syncthreads();
    if (threadIdx.x == 0)
        loss_out[0] = wsum[0] + wsum[1] + wsum[2] + wsum[3];
}

extern "C" void kernel_launch(void* const* d_in, const int* in_sizes, int n_in,
                              void* d_out, int out_size, void* d_ws, size_t ws_size,
                              hipStream_t stream) {
    const float* gate  = (const float*)d_in[0];  // [BATCH, FID]
    const float* bias  = (const float*)d_in[1];  // [FID]
    const float* gbias = (const float*)d_in[2];  // [1]
    const float* label = (const float*)d_in[3];  // [BATCH]
    float* out = (float*)d_out;                  // [logits | pred | loss]

    lr_rows<<<BATCH / ROWS, NT, 0, stream>>>(gate, bias, gbias, out);
    lr_loss<<<1, NT, 0, stream>>>(out, label, out + 2 * BATCH);
}

// Round 4
// 650.267 us; speedup vs baseline: 1.0426x; 1.0244x over previous
//
#include <hip/hip_runtime.h>
#include <math.h>

#define BATCH 2048
#define FID 65536
#define NT 256
#define ROWS 4                 // rows per block: bias vf4 reused 4x
#define NV (FID / 4)           // 16384 vf4 per row
#define KSPLIT 2
#define NVH (NV / KSPLIT)      // 8192 vf4 per block per row

typedef float vf4 __attribute__((ext_vector_type(4)));

// Partial-dot kernel: 1024 blocks = (BATCH/ROWS) row-groups x KSPLIT column
// halves -> 4 blocks/CU, 16 waves/CU for read-latency hiding. Each block
// accumulates ROWS partial dots over its column half and atomicAdds into the
// logits slots (2 addends per row -> bitwise-deterministic fp32 sum).
__global__ __launch_bounds__(NT) void lr_partial(
        const float* __restrict__ gate,
        const float* __restrict__ bias,
        float* __restrict__ out) {          // logits region, pre-zeroed
    const int kb = blockIdx.x & (KSPLIT - 1);
    const int rb = blockIdx.x >> 1;
    const int r0 = rb * ROWS;
    const vf4* __restrict__ b4 = (const vf4*)bias;
    const vf4* __restrict__ g4 = (const vf4*)gate + (size_t)r0 * NV;
    const int i0 = kb * NVH;
    const int i1 = i0 + NVH;

    float a0 = 0.f, a1 = 0.f, a2 = 0.f, a3 = 0.f;

    #pragma unroll 4
    for (int i = i0 + threadIdx.x; i < i1; i += NT) {
        vf4 v  = b4[i];
        vf4 g0 = __builtin_nontemporal_load(&g4[i]);
        vf4 g1 = __builtin_nontemporal_load(&g4[i + NV]);
        vf4 g2 = __builtin_nontemporal_load(&g4[i + 2 * NV]);
        vf4 g3 = __builtin_nontemporal_load(&g4[i + 3 * NV]);
        a0 = fmaf(g0.x, v.x, a0); a0 = fmaf(g0.y, v.y, a0);
        a0 = fmaf(g0.z, v.z, a0); a0 = fmaf(g0.w, v.w, a0);
        a1 = fmaf(g1.x, v.x, a1); a1 = fmaf(g1.y, v.y, a1);
        a1 = fmaf(g1.z, v.z, a1); a1 = fmaf(g1.w, v.w, a1);
        a2 = fmaf(g2.x, v.x, a2); a2 = fmaf(g2.y, v.y, a2);
        a2 = fmaf(g2.z, v.z, a2); a2 = fmaf(g2.w, v.w, a2);
        a3 = fmaf(g3.x, v.x, a3); a3 = fmaf(g3.y, v.y, a3);
        a3 = fmaf(g3.z, v.z, a3); a3 = fmaf(g3.w, v.w, a3);
    }

    #pragma unroll
    for (int off = 32; off > 0; off >>= 1) {
        a0 += __shfl_down(a0, off, 64);
        a1 += __shfl_down(a1, off, 64);
        a2 += __shfl_down(a2, off, 64);
        a3 += __shfl_down(a3, off, 64);
    }

    __shared__ float wsum[NT / 64][ROWS];
    const int wave = threadIdx.x >> 6;
    const int lane = threadIdx.x & 63;
    if (lane == 0) {
        wsum[wave][0] = a0; wsum[wave][1] = a1;
        wsum[wave][2] = a2; wsum[wave][3] = a3;
    }
    __syncthreads();

    if (threadIdx.x < ROWS) {
        const int r = threadIdx.x;
        float s = wsum[0][r] + wsum[1][r] + wsum[2][r] + wsum[3][r];
        atomicAdd(&out[r0 + r], s);
    }
}

// Finisher: add gbias, write final logits + pred, reduce loss. One block.
__global__ __launch_bounds__(NT) void lr_finish(
        const float* __restrict__ gbias,
        const float* __restrict__ label,
        float* __restrict__ out) {
    const float gb = gbias[0];
    float acc = 0.0f;
    for (int i = threadIdx.x; i < BATCH; i += NT) {
        float x = out[i] + gb;
        float l = label[i];
        out[i] = x;                                 // final logit
        out[BATCH + i] = 1.0f / (1.0f + expf(-x));  // pred
        acc += fmaxf(x, 0.0f) - x * l + log1pf(expf(-fabsf(x)));
    }
    #pragma unroll
    for (int off = 32; off > 0; off >>= 1)
        acc += __shfl_down(acc, off, 64);

    __shared__ float wsum[NT / 64];
    const int wave = threadIdx.x >> 6;
    const int lane = threadIdx.x & 63;
    if (lane == 0) wsum[wave] = acc;
    __syncthreads();
    if (threadIdx.x == 0)
        out[2 * BATCH] = wsum[0] + wsum[1] + wsum[2] + wsum[3];
}

extern "C" void kernel_launch(void* const* d_in, const int* in_sizes, int n_in,
                              void* d_out, int out_size, void* d_ws, size_t ws_size,
                              hipStream_t stream) {
    const float* gate  = (const float*)d_in[0];  // [BATCH, FID]
    const float* bias  = (const float*)d_in[1];  // [FID]
    const float* gbias = (const float*)d_in[2];  // [1]
    const float* label = (const float*)d_in[3];  // [BATCH]
    float* out = (float*)d_out;                  // [logits | pred | loss]

    // logits region is atomicAdd target -> zero it (d_out is poisoned 0xAA
    // before every timed launch). 8 KB, captured as a memset node.
    hipMemsetAsync(out, 0, BATCH * sizeof(float), stream);

    lr_partial<<<(BATCH / ROWS) * KSPLIT, NT, 0, stream>>>(gate, bias, out);
    lr_finish<<<1, NT, 0, stream>>>(gbias, label, out);
}